// Round 1
// 822.190 us; speedup vs baseline: 1.2447x; 1.2447x over previous
//
#include <hip/hip_runtime.h>
#include <cstdint>
#include <cstddef>

#define TSTEPS 1024
#define NB 256
#define NI 128
#define NH 128
#define NC 18
#define CH 32
#define NCHUNK (TSTEPS/CH)   // 32
#define XGS 516              // xgp row stride in f32: 4*129 -> rows 16B-aligned, quads split across banks

typedef _Float16 f16x8 __attribute__((ext_vector_type(8)));
typedef float    f32x4 __attribute__((ext_vector_type(4)));
typedef _Float16 half2_t __attribute__((ext_vector_type(2)));

__device__ __forceinline__ half2_t as_h2(uint32_t v){
  union { uint32_t u; half2_t h; } cv; cv.u = v; return cv.h;
}
__device__ __forceinline__ uint32_t pku(float a, float b){
  union { half2_t h; uint32_t u; } cv; cv.h.x=(_Float16)a; cv.h.y=(_Float16)b; return cv.u;
}
__device__ __forceinline__ float dot2f(half2_t a, half2_t b, float c){
#if __has_builtin(__builtin_amdgcn_fdot2)
  return __builtin_amdgcn_fdot2(a, b, c, false);
#else
  return c + (float)a.x*(float)b.x + (float)a.y*(float)b.y;
#endif
}
__device__ __forceinline__ float fast_rcp(float x){
#if __has_builtin(__builtin_amdgcn_rcpf)
  return __builtin_amdgcn_rcpf(x);
#else
  return 1.f / x;
#endif
}
// clamp-free sigmoid: exp(-v) -> inf/0 saturates rcp to 0/1; no NaN for finite v
__device__ __forceinline__ float sigm(float v){
  return fast_rcp(1.f + __expf(-v));
}
// tanh(v) = 1 - 2/(1+e^{2v}); saturates to +-1 at +-inf; no NaN for finite v
__device__ __forceinline__ float tanhx(float v){
  float r = fast_rcp(1.f + __expf(2.f*v));
  return __builtin_fmaf(-2.f, r, 1.f);
}
// 8 consecutive f32 -> f16x8 (one MFMA operand row-slice)
__device__ __forceinline__ f16x8 ldrow_f16(const float* base){
  float4 f0 = ((const float4*)base)[0];
  float4 f1 = ((const float4*)base)[1];
  f16x8 r;
  r[0]=(_Float16)f0.x; r[1]=(_Float16)f0.y; r[2]=(_Float16)f0.z; r[3]=(_Float16)f0.w;
  r[4]=(_Float16)f1.x; r[5]=(_Float16)f1.y; r[6]=(_Float16)f1.z; r[7]=(_Float16)f1.w;
  return r;
}
// lgkm-only workgroup barrier: all in-loop cross-wave deps are LDS, so skip the
// vmcnt(0)/expcnt drain __syncthreads would emit -> global prefetch/stores stay in flight.
__device__ __forceinline__ void barrier_lds(){
  asm volatile("s_waitcnt lgkmcnt(0)" ::: "memory");
  __builtin_amdgcn_s_barrier();
}

// One block per batch row, 512 threads (8 waves).
// Wave w, gate-type q, cell = w*16 + n (n=lane&15). Recurrent step = 16 MFMA/wave,
// M=1 used of 16; i,f,g,o for a cell land in the SAME lane -> in-lane activation.
// Wih AND Whh both persistent in VGPRs (64+64 regs). x-gates staged in LDS as
// [tt][cell*4+q] so each step reads ONE ds_read_b128. hist[] is the h ring buffer.
__global__ __launch_bounds__(512, 2) void lstm_mfma(
    const float* __restrict__ x,      // [T,B,I]
    const float* __restrict__ h0,     // [B,H]
    const float* __restrict__ c0,     // [B,H]
    const float* __restrict__ Wih,    // [4H,I]
    const float* __restrict__ Whh,    // [4H,H]
    const float* __restrict__ bih,    // [4H]
    const float* __restrict__ bhh,    // [4H]
    const float* __restrict__ fcW,    // [18,H]
    const float* __restrict__ fcb,    // [18]
    float* __restrict__ out,          // [T,B,18]
    float* __restrict__ hT,           // [B,H]
    float* __restrict__ cT)           // [B,H]
{
  const int b    = blockIdx.x;
  const int tid  = threadIdx.x;
  const int w    = tid >> 6;      // wave 0..7
  const int l    = tid & 63;
  const int n    = l & 15;        // tile col
  const int quad = l >> 4;        // k-chunk within frag

  __shared__ __align__(16) _Float16 xs[CH][136];    // x chunk f16 (+pad)      8704 B
  __shared__ __align__(16) float    xgp[CH][XGS];   // x-gates f32, gate-contig 66048 B
  __shared__ __align__(16) _Float16 hist[CH][128];  // h ring buffer / history  8192 B
  __shared__ __align__(16) uint32_t fcw[NC][66];    // head W f16 (+pad)        4752 B

  // ---- persistent weight B-frags: Whh + Wih, [q][kt], 128 VGPRs ----
  f16x8 whh[4][4], wih[4][4];
#pragma unroll
  for (int q = 0; q < 4; ++q){
    const int row = q*128 + w*16 + n;
#pragma unroll
    for (int kt = 0; kt < 4; ++kt){
      whh[q][kt] = ldrow_f16(Whh + (size_t)row*NH + kt*32 + quad*8);
      wih[q][kt] = ldrow_f16(Wih + (size_t)row*NI + kt*32 + quad*8);
    }
  }
  float biasq[4];
#pragma unroll
  for (int q = 0; q < 4; ++q){
    const int g = q*128 + w*16 + n;
    biasq[q] = bih[g] + bhh[g];
  }
  float cst = c0[(size_t)b*NH + w*16 + n];   // valid lanes l<16

  if (tid < 128) hist[CH-1][tid] = (_Float16)h0[(size_t)b*NH + tid];  // h ring seed
#pragma unroll
  for (int r = 0; r < 3; ++r){
    int idx = tid + 512*r;                   // 18*64 = 1152 targets
    if (idx < NC*64){
      int j = idx >> 6, k = idx & 63;
      float2 f = ((const float2*)(fcW + (size_t)j*NH))[k];
      fcw[j][k] = pku(f.x, f.y);
    }
  }

  // ---- prefetch x chunk 0 into registers ----
  const int ttA = tid >> 5;                  // 0..15
  const int ttB = ttA + 16;                  // 16..31
  const int k4  = tid & 31;
  float4 xpA = ((const float4*)(x + ((size_t)ttA*NB + b)*NI))[k4];
  float4 xpB = ((const float4*)(x + ((size_t)ttB*NB + b)*NI))[k4];
  __syncthreads();

  f16x8 afr[4] = { (f16x8)(_Float16)0, (f16x8)(_Float16)0,
                   (f16x8)(_Float16)0, (f16x8)(_Float16)0 };
  float hlast = 0.f;

#pragma unroll 1
  for (int ck = 0; ck < NCHUNK; ++ck){
    const int t0 = ck*CH;

    // ---------- xs <- prefetched registers (f16) ----------
    {
      union { _Float16 h[4]; uint2 u2; } pa, pb;
      pa.h[0]=(_Float16)xpA.x; pa.h[1]=(_Float16)xpA.y;
      pa.h[2]=(_Float16)xpA.z; pa.h[3]=(_Float16)xpA.w;
      *(uint2*)&xs[ttA][4*k4] = pa.u2;
      pb.h[0]=(_Float16)xpB.x; pb.h[1]=(_Float16)xpB.y;
      pb.h[2]=(_Float16)xpB.z; pb.h[3]=(_Float16)xpB.w;
      *(uint2*)&xs[ttB][4*k4] = pb.u2;
    }
    barrier_lds();   // xs ready; also orders prev head's hist reads before new hist writes

    // ---------- x-GEMM: XG[32,512] = X @ Wih^T + bias (MFMA, weights in regs) ----------
    {
      f16x8 xa[2][4];                        // A-frags [mt][kt]
#pragma unroll
      for (int mt = 0; mt < 2; ++mt)
#pragma unroll
        for (int kt = 0; kt < 4; ++kt)
          xa[mt][kt] = *(const f16x8*)&xs[mt*16 + n][kt*32 + quad*8];

#pragma unroll
      for (int q = 0; q < 4; ++q){
#pragma unroll
        for (int mt = 0; mt < 2; ++mt){
          f32x4 acc = { biasq[q], biasq[q], biasq[q], biasq[q] };
#pragma unroll
          for (int kt = 0; kt < 4; ++kt)
            acc = __builtin_amdgcn_mfma_f32_16x16x32_f16(xa[mt][kt], wih[q][kt], acc, 0, 0, 0);
#pragma unroll
          for (int r = 0; r < 4; ++r)
            xgp[mt*16 + quad*4 + r][(w*16 + n)*4 + q] = acc[r];
        }
      }
    }

    // issue next chunk's x loads now; lgkm-only barriers keep them in flight
    // through the whole recurrent phase (latency fully hidden)
    if (ck + 1 < NCHUNK){
      const size_t t1 = (size_t)(t0 + CH);
      xpA = ((const float4*)(x + ((t1 + ttA)*NB + b)*NI))[k4];
      xpB = ((const float4*)(x + ((t1 + ttB)*NB + b)*NI))[k4];
    }
    barrier_lds();   // xgp ready

    // ---------- 32 recurrent steps ----------
#pragma unroll 4
    for (int tt = 0; tt < CH; ++tt){
      // all 4 gate seeds for this lane's cell in ONE b128 (quads broadcast, free)
      f32x4 sgv = *(const f32x4*)&xgp[tt][(w*16 + n)*4];
      const int rp = (tt + CH - 1) & (CH - 1);   // previous h in the ring
      if (n == 0){                               // lanes 0,16,32,48 hold the real A row
#pragma unroll
        for (int kt = 0; kt < 4; ++kt)
          afr[kt] = *(const f16x8*)&hist[rp][kt*32 + quad*8];
      }
      float gate[4];
#pragma unroll
      for (int q = 0; q < 4; ++q){
        // only C/D row 0 (lanes 0-15, reg 0) is consumed: seed just element 0,
        // leave the rest undefined (rows 1-15 are finite garbage, never read)
        f32x4 aA; aA[0] = sgv[q];
        aA = __builtin_amdgcn_mfma_f32_16x16x32_f16(afr[0], whh[q][0], aA, 0, 0, 0);
        aA = __builtin_amdgcn_mfma_f32_16x16x32_f16(afr[1], whh[q][1], aA, 0, 0, 0);
        f32x4 aB; aB[0] = 0.f;
        aB = __builtin_amdgcn_mfma_f32_16x16x32_f16(afr[2], whh[q][2], aB, 0, 0, 0);
        aB = __builtin_amdgcn_mfma_f32_16x16x32_f16(afr[3], whh[q][3], aB, 0, 0, 0);
        gate[q] = aA[0] + aB[0];
      }
      if (l < 16){
        float iv = sigm(gate[0]);
        float fv = sigm(gate[1]);
        float gv = tanhx(gate[2]);
        float ov = sigm(gate[3]);
        cst = __builtin_fmaf(fv, cst, iv*gv);
        float hv = ov * tanhx(cst);
        hlast = hv;
        hist[tt][w*16 + l] = (_Float16)hv;
      }
      barrier_lds();
      (void)rp;
    }

    // ---------- fused head for this chunk (reads hist, no trailing barrier:
    // next iteration's xs barrier orders these reads before hist is rewritten) ----------
    {
      const int tt = tid >> 4;               // 0..31
      const int jb = tid & 15;
      const uint4* hb = (const uint4*)&hist[tt][0];
#pragma unroll
      for (int jj = 0; jj < 2; ++jj){
        const int j = jj*16 + jb;
        if (j < NC){
          const uint2* fw = (const uint2*)&fcw[j][0];
          float a0=0.f, a1=0.f, a2=0.f, a3=0.f;
#pragma unroll
          for (int q = 0; q < 4; ++q){
            uint4 v0 = hb[q], v1 = hb[4+q], v2 = hb[8+q], v3 = hb[12+q];
            uint2 f0a = fw[2*q],    f0b = fw[2*q+1];
            uint2 f1a = fw[8+2*q],  f1b = fw[8+2*q+1];
            uint2 f2a = fw[16+2*q], f2b = fw[16+2*q+1];
            uint2 f3a = fw[24+2*q], f3b = fw[24+2*q+1];
            a0 = dot2f(as_h2(f0a.x), as_h2(v0.x), a0);
            a1 = dot2f(as_h2(f1a.x), as_h2(v1.x), a1);
            a2 = dot2f(as_h2(f2a.x), as_h2(v2.x), a2);
            a3 = dot2f(as_h2(f3a.x), as_h2(v3.x), a3);
            a0 = dot2f(as_h2(f0a.y), as_h2(v0.y), a0);
            a1 = dot2f(as_h2(f1a.y), as_h2(v1.y), a1);
            a2 = dot2f(as_h2(f2a.y), as_h2(v2.y), a2);
            a3 = dot2f(as_h2(f3a.y), as_h2(v3.y), a3);
            a0 = dot2f(as_h2(f0b.x), as_h2(v0.z), a0);
            a1 = dot2f(as_h2(f1b.x), as_h2(v1.z), a1);
            a2 = dot2f(as_h2(f2b.x), as_h2(v2.z), a2);
            a3 = dot2f(as_h2(f3b.x), as_h2(v3.z), a3);
            a0 = dot2f(as_h2(f0b.y), as_h2(v0.w), a0);
            a1 = dot2f(as_h2(f1b.y), as_h2(v1.w), a1);
            a2 = dot2f(as_h2(f2b.y), as_h2(v2.w), a2);
            a3 = dot2f(as_h2(f3b.y), as_h2(v3.w), a3);
          }
          out[(size_t)(t0+tt)*NB*NC + (size_t)b*NC + j] =
              (a0+a1) + (a2+a3) + fcb[j];
        }
      }
    }
  }

  // ---------- final hT / cT (from registers) ----------
  if (l < 16){
    hT[(size_t)b*NH + w*16 + l] = hlast;
    cT[(size_t)b*NH + w*16 + l] = cst;
  }
}

extern "C" void kernel_launch(void* const* d_in, const int* in_sizes, int n_in,
                              void* d_out, int out_size, void* d_ws, size_t ws_size,
                              hipStream_t stream) {
  (void)in_sizes; (void)n_in; (void)d_ws; (void)ws_size; (void)out_size;
  const float* x   = (const float*)d_in[0];
  const float* h0  = (const float*)d_in[1];
  const float* c0  = (const float*)d_in[2];
  const float* Wih = (const float*)d_in[3];
  const float* Whh = (const float*)d_in[4];
  const float* bih = (const float*)d_in[5];
  const float* bhh = (const float*)d_in[6];
  const float* fcW = (const float*)d_in[7];
  const float* fcb = (const float*)d_in[8];
  float* out = (float*)d_out;
  float* hT  = out + (size_t)TSTEPS*NB*NC;   // 4,718,592
  float* cT  = hT + (size_t)NB*NH;           // +32,768
  hipLaunchKernelGGL(lstm_mfma, dim3(NB), dim3(512), 0, stream,
                     x, h0, c0, Wih, Whh, bih, bhh, fcW, fcb, out, hT, cT);
}